// Round 2
// baseline (399.421 us; speedup 1.0000x reference)
//
#include <hip/hip_runtime.h>

// ---------------------------------------------------------------------------
// Stage2Loss v2: latency-bound fix. 2 blocks per batch (half=0: d_error +
// circuit pairs [+ l_node]; half=1: d_hw_norm + cross pairs). LDS holds only
// double-buffered T (53KB -> 2 blocks/CU). D-frags + gather-P come from
// global (L1/L2 path, concurrent with LDS unit). P frags register-resident.
// ---------------------------------------------------------------------------

typedef __attribute__((ext_vector_type(8))) short short8;
typedef __attribute__((ext_vector_type(4))) float float4_;
typedef __attribute__((ext_vector_type(2))) unsigned int uint2_;

#define HDIM 256
#define LDIM 200

// ws float-index layout:
//  [0] S_surr  [1] S_sep  [2] S_node  [3] inv_qi_sum  [5] dhw_max (uint bits)
//  [16..271] q[256]
//  byte 2048: DcatT bf16 [512][256]; row c = Dcat column c
#define WS_DCAT_BYTE_OFF 2048

__device__ __forceinline__ unsigned short f2b(float f) {  // RNE f32->bf16
  unsigned int u = __float_as_uint(f);
  return (unsigned short)((u + 0x7FFFu + ((u >> 16) & 1u)) >> 16);
}
__device__ __forceinline__ float b2f(unsigned short u) {
  return __uint_as_float(((unsigned int)u) << 16);
}
__device__ __forceinline__ short8 pack8(float4_ a0, float4_ a1) {
  short8 f;
  f[0] = (short)f2b(a0[0]); f[1] = (short)f2b(a0[1]);
  f[2] = (short)f2b(a0[2]); f[3] = (short)f2b(a0[3]);
  f[4] = (short)f2b(a1[0]); f[5] = (short)f2b(a1[1]);
  f[6] = (short)f2b(a1[2]); f[7] = (short)f2b(a1[3]);
  return f;
}

// ---------------- scal0: q MLP, inv qi-sum, zero accumulators ---------------
__global__ void s2l_scal0(const float* __restrict__ feat, const float* __restrict__ W1,
                          const float* __restrict__ bias1, const float* __restrict__ W2,
                          const float* __restrict__ bias2, const float* __restrict__ qi,
                          float* __restrict__ ws) {
  __shared__ float red[4];
  const int tid = threadIdx.x;  // 256
  float f0 = feat[tid * 5 + 0], f1 = feat[tid * 5 + 1], f2 = feat[tid * 5 + 2];
  float f3 = feat[tid * 5 + 3], f4 = feat[tid * 5 + 4];
  float s = bias2[0];
#pragma unroll
  for (int j = 0; j < 32; ++j) {
    float hd = bias1[j] + f0 * W1[j] + f1 * W1[32 + j] + f2 * W1[64 + j] +
               f3 * W1[96 + j] + f4 * W1[128 + j];
    s += fmaxf(hd, 0.f) * W2[j];
  }
  ws[16 + tid] = 1.f / (1.f + expf(-s));
  float v = (tid < LDIM) ? qi[tid] : 0.f;
#pragma unroll
  for (int off = 32; off > 0; off >>= 1) v += __shfl_down(v, off);
  if ((tid & 63) == 0) red[tid >> 6] = v;
  __syncthreads();
  if (tid == 0) {
    ws[3] = 1.f / fmaxf(red[0] + red[1] + red[2] + red[3], 1e-8f);
    ws[0] = 0.f; ws[1] = 0.f; ws[2] = 0.f;
    ((unsigned int*)ws)[5] = 0u;  // dmax accumulator (floats >= 0)
  }
}

// ---------------- dmax: grid-wide max(d_hw) via uint atomicMax --------------
__global__ void s2l_dmax(const float* __restrict__ dhw, float* __restrict__ ws) {
  const int idx = blockIdx.x * 256 + threadIdx.x;  // 64 blocks x 256 thr x 4 f
  float4_ v = *(const float4_*)(dhw + idx * 4);
  float m = fmaxf(fmaxf(v[0], v[1]), fmaxf(v[2], v[3]));
#pragma unroll
  for (int off = 32; off > 0; off >>= 1) m = fmaxf(m, __shfl_down(m, off));
  if ((threadIdx.x & 63) == 0) atomicMax(((unsigned int*)ws) + 5, __float_as_uint(m));
}

// ------- dcat: coalesced 64x64 transpose -> DcatT bf16 [512 c][256 h] -------
__global__ void s2l_dcat(const float* __restrict__ derr, const float* __restrict__ dhw,
                         const float* __restrict__ ws, unsigned short* __restrict__ DcatT) {
  __shared__ float tile[64][65];
  const int ct = blockIdx.x;  // 0..7 : 64-col group of Dcat (0..3 err, 4..7 hw)
  const int ht = blockIdx.y;  // 0..3 : 64-row group of h
  float inv = 1.f;
  if (ct >= 4) {
    float mx = __uint_as_float(((const unsigned int*)ws)[5]);
    inv = 1.f / fmaxf(mx, 1e-8f);
  }
  const float* src = (ct < 4) ? derr : dhw;
  const int c0 = (ct & 3) * 64;
#pragma unroll
  for (int k = 0; k < 16; ++k) {
    int idx = k * 256 + threadIdx.x;
    int lh = idx >> 6, lc = idx & 63;
    tile[lh][lc] = src[(ht * 64 + lh) * 256 + c0 + lc] * inv;
  }
  __syncthreads();
#pragma unroll
  for (int k = 0; k < 16; ++k) {
    int idx = k * 256 + threadIdx.x;
    int lc = idx >> 6, lh = idx & 63;
    DcatT[(size_t)(ct * 64 + lc) * HDIM + ht * 64 + lh] = f2b(tile[lh][lc]);
  }
}

// ------------------------------- main kernel --------------------------------
#define TROWS 208
#define TSTRIDE 128                       // bytes per T row (64 bf16)
#define TBYTES (TROWS * TSTRIDE)          // 26624
#define LDS_BYTES (2 * TBYTES + 64)       // + reduce scratch

__global__ __launch_bounds__(512, 4) void s2l_main(
    const float* __restrict__ P, const int* __restrict__ cpairs,
    const int* __restrict__ xpairs, const float* __restrict__ qi,
    float* __restrict__ ws, const unsigned short* __restrict__ DcatT) {
  __shared__ __attribute__((aligned(16))) unsigned char smem[LDS_BYTES];
  const int tid = threadIdx.x;
  const int wave = tid >> 6, lane = tid & 63;
  const int ncol = lane & 15, kg = lane >> 4;
  const int half = blockIdx.x >> 9;   // 0: err/circuit, 1: hw/cross
  const int b = blockIdx.x & 511;
  const float* Pb = P + (size_t)b * (HDIM * HDIM);
  const unsigned short* Dh = DcatT + (size_t)half * 256 * HDIM;

  // ---- P fragments (register-resident, B operand) + fused l_node ----
  short8 pf[2][8];
  const int row0 = wave * 16 + ncol;        // tiles 0..7  -> rows 0..127
  const int row1 = 128 + wave * 16 + ncol;  // tiles 8..12 -> rows 128..207
  const bool v1 = (wave < 5);
  float ln0 = 0.f, ln1 = 0.f;
  const float* qv = ws + 16;
#pragma unroll
  for (int ks = 0; ks < 8; ++ks) {
    const int h0 = ks * 32 + kg * 8;
    float4_ a0 = *(const float4_*)(Pb + row0 * HDIM + h0);
    float4_ a1 = *(const float4_*)(Pb + row0 * HDIM + h0 + 4);
    pf[0][ks] = pack8(a0, a1);
    if (half == 0) {
      float4_ q0 = *(const float4_*)(qv + h0);
      float4_ q1 = *(const float4_*)(qv + h0 + 4);
      ln0 += a0[0] * q0[0] + a0[1] * q0[1] + a0[2] * q0[2] + a0[3] * q0[3] +
             a1[0] * q1[0] + a1[1] * q1[1] + a1[2] * q1[2] + a1[3] * q1[3];
      if (v1) {
        float4_ c0 = *(const float4_*)(Pb + row1 * HDIM + h0);
        float4_ c1 = *(const float4_*)(Pb + row1 * HDIM + h0 + 4);
        pf[1][ks] = pack8(c0, c1);
        ln1 += c0[0] * q0[0] + c0[1] * q0[1] + c0[2] * q0[2] + c0[3] * q0[3] +
               c1[0] * q1[0] + c1[1] * q1[1] + c1[2] * q1[2] + c1[3] * q1[3];
      } else {
        pf[1][ks] = (short8){0, 0, 0, 0, 0, 0, 0, 0};
      }
    } else {
      if (v1) {
        float4_ c0 = *(const float4_*)(Pb + row1 * HDIM + h0);
        float4_ c1 = *(const float4_*)(Pb + row1 * HDIM + h0 + 4);
        pf[1][ks] = pack8(c0, c1);
      } else {
        pf[1][ks] = (short8){0, 0, 0, 0, 0, 0, 0, 0};
      }
    }
  }
  float lnode = 0.f;
  if (half == 0) {
    const float inv_qs = ws[3];
    float w0 = qi[row0] * inv_qs;  // row0 < 128 always valid
    float w1 = (v1 && row1 < LDIM) ? qi[row1] * inv_qs : 0.f;
    lnode = ln0 * w0 + ln1 * w1;
  }

  // ---- pair indices (this block's flavor only) ----
  const int* pr = half ? xpairs : cpairs;
  const int pi = pr[2 * tid], pj = pr[2 * tid + 1];
  const int piswz = (pi & 7) << 4;

  float gsum = 0.f;
#pragma unroll 1
  for (int ct = 0; ct < 4; ++ct) {
    unsigned char* Tbuf = smem + (ct & 1) * TBYTES;
    // ---- MFMA: T[prow][kcol] = sum_h D[h][ct*64+kcol] * P[prow][h]
    float4_ acc[2][4];
#pragma unroll
    for (int nt = 0; nt < 2; ++nt)
#pragma unroll
      for (int mt = 0; mt < 4; ++mt) acc[nt][mt] = (float4_){0.f, 0.f, 0.f, 0.f};
#pragma unroll
    for (int ks = 0; ks < 8; ++ks) {
      short8 af[4];
#pragma unroll
      for (int mt = 0; mt < 4; ++mt) {
        const int c = ct * 64 + mt * 16 + ncol;
        af[mt] = *(const short8*)(Dh + (size_t)c * HDIM + ks * 32 + kg * 8);
      }
#pragma unroll
      for (int mt = 0; mt < 4; ++mt)
        acc[0][mt] = __builtin_amdgcn_mfma_f32_16x16x32_bf16(af[mt], pf[0][ks],
                                                             acc[0][mt], 0, 0, 0);
      if (v1) {
#pragma unroll
        for (int mt = 0; mt < 4; ++mt)
          acc[1][mt] = __builtin_amdgcn_mfma_f32_16x16x32_bf16(af[mt], pf[1][ks],
                                                               acc[1][mt], 0, 0, 0);
      }
    }
    // ---- T writes: lane holds kcol = mt*16 + kg*4 + reg (4 consecutive)
#pragma unroll
    for (int nt = 0; nt < 2; ++nt) {
      if (nt == 1 && !v1) break;  // wave-uniform
      const int prow = nt ? row1 : row0;
#pragma unroll
      for (int mt = 0; mt < 4; ++mt) {
        uint2_ pk;
        pk[0] = (unsigned int)f2b(acc[nt][mt][0]) | ((unsigned int)f2b(acc[nt][mt][1]) << 16);
        pk[1] = (unsigned int)f2b(acc[nt][mt][2]) | ((unsigned int)f2b(acc[nt][mt][3]) << 16);
        const int slot = mt * 2 + (kg >> 1), off8 = (kg & 1) * 8;
        *(uint2_*)(Tbuf + prow * TSTRIDE + ((slot ^ (prow & 7)) << 4) + off8) = pk;
      }
    }
    __syncthreads();  // T[ct&1] visible; gather(ct-1) of other buffer done
    // ---- gather: thread = pair; T row (LDS bf16) . P[j] row (global f32)
    {
      const float* Pj = Pb + pj * HDIM + ct * 64;
      const unsigned char* Ti = Tbuf + pi * TSTRIDE;
      float g = 0.f;
#pragma unroll
      for (int s = 0; s < 8; ++s) {
        short8 tv = *(const short8*)(Ti + (((s << 4)) ^ piswz));
        float4_ p0 = *(const float4_*)(Pj + s * 8);
        float4_ p1 = *(const float4_*)(Pj + s * 8 + 4);
#pragma unroll
        for (int e = 0; e < 4; ++e) {
          g += b2f((unsigned short)tv[e]) * p0[e];
          g += b2f((unsigned short)tv[e + 4]) * p1[e];
        }
      }
      gsum += g;
    }
    // no second barrier: next ct writes the other T buffer; this buffer is
    // only rewritten at ct+2, after the ct+1 barrier.
  }

  // ---- block reduction + atomics ----
#pragma unroll
  for (int off = 32; off > 0; off >>= 1) {
    gsum += __shfl_down(gsum, off);
    lnode += __shfl_down(lnode, off);
  }
  float* red = (float*)(smem + 2 * TBYTES);
  if (lane == 0) { red[wave * 2] = gsum; red[wave * 2 + 1] = lnode; }
  __syncthreads();
  if (tid == 0) {
    float g = 0.f, l = 0.f;
    for (int w = 0; w < 8; ++w) { g += red[2 * w]; l += red[2 * w + 1]; }
    atomicAdd(&ws[half], g);            // [0]=surr, [1]=sep
    if (half == 0) atomicAdd(&ws[2], l);
  }
}

// ------------------------------ final combine -------------------------------
__global__ void s2l_final(const float* __restrict__ ws, float* __restrict__ out) {
  if (threadIdx.x == 0) {
    const float inv_be = 1.f / (512.f * 512.f);
    float l_surr = ws[0] * inv_be;
    float l_sep = -ws[1] * inv_be;
    float l_node = -ws[2] / 512.f;
    out[0] = l_surr + 0.3f * l_node + 0.1f * l_sep;
    out[1] = l_surr;
    out[2] = l_node;
    out[3] = l_sep;
  }
}

extern "C" void kernel_launch(void* const* d_in, const int* in_sizes, int n_in,
                              void* d_out, int out_size, void* d_ws, size_t ws_size,
                              hipStream_t stream) {
  (void)in_sizes; (void)n_in; (void)out_size; (void)ws_size;
  const float* P     = (const float*)d_in[0];
  const float* d_err = (const float*)d_in[1];
  const float* d_hw  = (const float*)d_in[2];
  const float* feat  = (const float*)d_in[3];
  const float* qi    = (const float*)d_in[4];
  const float* W1    = (const float*)d_in[5];
  const float* bias1 = (const float*)d_in[6];
  const float* W2    = (const float*)d_in[7];
  const float* bias2 = (const float*)d_in[8];
  const int* cpairs  = (const int*)d_in[9];
  const int* xpairs  = (const int*)d_in[10];
  float* ws = (float*)d_ws;
  unsigned short* DcatT = (unsigned short*)((char*)d_ws + WS_DCAT_BYTE_OFF);
  float* out = (float*)d_out;

  s2l_scal0<<<dim3(1), dim3(256), 0, stream>>>(feat, W1, bias1, W2, bias2, qi, ws);
  s2l_dmax<<<dim3(64), dim3(256), 0, stream>>>(d_hw, ws);
  s2l_dcat<<<dim3(8, 4), dim3(256), 0, stream>>>(d_err, d_hw, ws, DcatT);
  s2l_main<<<dim3(1024), dim3(512), 0, stream>>>(P, cpairs, xpairs, qi, ws, DcatT);
  s2l_final<<<dim3(1), dim3(64), 0, stream>>>(ws, out);
}

// Round 3
// 339.226 us; speedup vs baseline: 1.1774x; 1.1774x over previous
//
#include <hip/hip_runtime.h>

// ---------------------------------------------------------------------------
// Stage2Loss v3: R1 core (per-batch MFMA GEMM fused with gathered pair dots,
// everything LDS-resident) with latency fixes:
//   - D fragments read from global (L1/L2-hot), not LDS: -32KB LDS, -8 barriers
//   - T double-buffered: one barrier per ct (9 total)
//   - octet gather: 8 lanes/pair, slice s=tid&7, conflict-free bank coverage
//   - v_dot2_f32_bf16 for gather dot (guarded)
// ---------------------------------------------------------------------------

typedef __attribute__((ext_vector_type(8))) short short8;
typedef __attribute__((ext_vector_type(4))) float float4_;
typedef __attribute__((ext_vector_type(2))) unsigned int uint2_;
typedef __attribute__((ext_vector_type(4))) unsigned int uint4_;

#define HDIM 256
#define LDIM 200

// ws float-index layout:
//  [0] S_surr [1] S_sep [2] S_node [3] inv_qi_sum [5] dhw_max (uint bits)
//  [16..271] q[256]
//  byte 2048: DcatT bf16 [512][256]; row c = Dcat column c
#define WS_DCAT_BYTE_OFF 2048

__device__ __forceinline__ unsigned short f2b(float f) {  // RNE f32->bf16
  unsigned int u = __float_as_uint(f);
  return (unsigned short)((u + 0x7FFFu + ((u >> 16) & 1u)) >> 16);
}
__device__ __forceinline__ float b2f(unsigned short u) {
  return __uint_as_float(((unsigned int)u) << 16);
}

#if defined(__has_builtin)
#if __has_builtin(__builtin_amdgcn_fdot2_f32_bf16)
#define HAVE_FDOT2 1
#endif
#endif
#ifdef HAVE_FDOT2
typedef __attribute__((ext_vector_type(2))) __bf16 bf16x2;
#endif

__device__ __forceinline__ float dot8acc(uint4_ a, uint4_ b, float acc) {
#ifdef HAVE_FDOT2
#pragma unroll
  for (int d = 0; d < 4; ++d) {
    union { unsigned int u; bf16x2 v; } ua, ub;
    ua.u = a[d]; ub.u = b[d];
    acc = __builtin_amdgcn_fdot2_f32_bf16(ua.v, ub.v, acc, false);
  }
#else
#pragma unroll
  for (int d = 0; d < 4; ++d) {
    float alo = __uint_as_float(a[d] << 16);
    float ahi = __uint_as_float(a[d] & 0xffff0000u);
    float blo = __uint_as_float(b[d] << 16);
    float bhi = __uint_as_float(b[d] & 0xffff0000u);
    acc = fmaf(alo, blo, acc);
    acc = fmaf(ahi, bhi, acc);
  }
#endif
  return acc;
}

// -------- prep: block0 = q MLP + qi-sum; blocks 1..64 = d_hw max ------------
__global__ void s2l_prep(const float* __restrict__ feat, const float* __restrict__ W1,
                         const float* __restrict__ bias1, const float* __restrict__ W2,
                         const float* __restrict__ bias2, const float* __restrict__ qi,
                         const float* __restrict__ dhw, float* __restrict__ ws) {
  const int tid = threadIdx.x;  // 256
  if (blockIdx.x == 0) {
    __shared__ float red[4];
    float f0 = feat[tid * 5 + 0], f1 = feat[tid * 5 + 1], f2 = feat[tid * 5 + 2];
    float f3 = feat[tid * 5 + 3], f4 = feat[tid * 5 + 4];
    float s = bias2[0];
#pragma unroll
    for (int j = 0; j < 32; ++j) {
      float hd = bias1[j] + f0 * W1[j] + f1 * W1[32 + j] + f2 * W1[64 + j] +
                 f3 * W1[96 + j] + f4 * W1[128 + j];
      s += fmaxf(hd, 0.f) * W2[j];
    }
    ws[16 + tid] = 1.f / (1.f + expf(-s));
    float v = (tid < LDIM) ? qi[tid] : 0.f;
#pragma unroll
    for (int off = 32; off > 0; off >>= 1) v += __shfl_down(v, off);
    if ((tid & 63) == 0) red[tid >> 6] = v;
    __syncthreads();
    if (tid == 0) ws[3] = 1.f / fmaxf(red[0] + red[1] + red[2] + red[3], 1e-8f);
  } else {
    const int idx = (blockIdx.x - 1) * 1024 + tid * 4;  // 64 blocks x 1024 f
    float4_ v = *(const float4_*)(dhw + idx);
    float m = fmaxf(fmaxf(v[0], v[1]), fmaxf(v[2], v[3]));
#pragma unroll
    for (int off = 32; off > 0; off >>= 1) m = fmaxf(m, __shfl_down(m, off));
    if ((tid & 63) == 0) atomicMax(((unsigned int*)ws) + 5, __float_as_uint(m));
  }
}

// ------- dcat: coalesced 64x64 transpose -> DcatT bf16 [512 c][256 h] -------
__global__ void s2l_dcat(const float* __restrict__ derr, const float* __restrict__ dhw,
                         const float* __restrict__ ws, unsigned short* __restrict__ DcatT) {
  __shared__ float tile[64][65];
  const int ct = blockIdx.x;  // 0..7 : 64-col group (0..3 err, 4..7 hw)
  const int ht = blockIdx.y;  // 0..3 : 64-row group of h
  float inv = 1.f;
  if (ct >= 4) {
    float mx = __uint_as_float(((const unsigned int*)ws)[5]);
    inv = 1.f / fmaxf(mx, 1e-8f);
  }
  const float* src = (ct < 4) ? derr : dhw;
  const int c0 = (ct & 3) * 64;
#pragma unroll
  for (int k = 0; k < 16; ++k) {
    int idx = k * 256 + threadIdx.x;
    int lh = idx >> 6, lc = idx & 63;
    tile[lh][lc] = src[(ht * 64 + lh) * 256 + c0 + lc] * inv;
  }
  __syncthreads();
#pragma unroll
  for (int k = 0; k < 16; ++k) {
    int idx = k * 256 + threadIdx.x;
    int lc = idx >> 6, lh = idx & 63;
    DcatT[(size_t)(ct * 64 + lc) * HDIM + ht * 64 + lh] = f2b(tile[lh][lc]);
  }
}

// ------------------------------- main kernel --------------------------------
// LDS: P 200x256 bf16 swizzled (100KB) | T double-buffered 2 x 208x64 bf16
#define P_OFF 0
#define T_OFF 102400
#define TSTRIDE 128
#define TBYTES (208 * TSTRIDE)                    // 26624
#define RED_OFF (T_OFF + 2 * TBYTES)              // 155648
#define LDS_BYTES (RED_OFF + 64)                  // 155712

__global__ __launch_bounds__(512, 2) void s2l_main(
    const float* __restrict__ P, const int* __restrict__ cpairs,
    const int* __restrict__ xpairs, const float* __restrict__ qi,
    float* __restrict__ ws, const unsigned short* __restrict__ DcatT) {
  __shared__ __attribute__((aligned(16))) unsigned char smem[LDS_BYTES];
  const int tid = threadIdx.x;
  const int wave = tid >> 6, lane = tid & 63;
  const int b = blockIdx.x;
  const int nq = wave >> 1;   // 0..3 : P-row tile quarter (N side)
  const int mg = wave & 1;    // 0..1 : Dcat-col half within 64-col tile
  const int ncol = lane & 15; // within-tile index
  const int kg = lane >> 4;   // 0..3 k-group

  // --- per-thread loop-invariant q slice (slot s = tid&31 every iteration)
  const int s0 = (tid & 31) * 8;
  float qreg[8];
#pragma unroll
  for (int e = 0; e < 8; ++e) qreg[e] = ws[16 + s0 + e];
  const float inv_qs = ws[3];

  // --- stage P_log[b] -> bf16 LDS (swizzled) + fused l_node partial
  const float* Pb = P + (size_t)b * (HDIM * HDIM);
  float lnode = 0.f;
  for (int sg = tid; sg < LDIM * 32; sg += 512) {  // 6400 16B-slots
    int row = sg >> 5, s = sg & 31;
    float4_ a0 = *(const float4_*)(Pb + row * HDIM + s * 8);
    float4_ a1 = *(const float4_*)(Pb + row * HDIM + s * 8 + 4);
    short8 v;
    v[0] = (short)f2b(a0[0]); v[1] = (short)f2b(a0[1]);
    v[2] = (short)f2b(a0[2]); v[3] = (short)f2b(a0[3]);
    v[4] = (short)f2b(a1[0]); v[5] = (short)f2b(a1[1]);
    v[6] = (short)f2b(a1[2]); v[7] = (short)f2b(a1[3]);
    int swz = (s & 24) | ((s & 7) ^ (row & 7));
    *(short8*)(smem + P_OFF + row * 512 + swz * 16) = v;
    float vq = a0[0] * qreg[0] + a0[1] * qreg[1] + a0[2] * qreg[2] + a0[3] * qreg[3] +
               a1[0] * qreg[4] + a1[1] * qreg[5] + a1[2] * qreg[6] + a1[3] * qreg[7];
    lnode += vq * (qi[row] * inv_qs);
  }
  // zero pad rows 200..207 (keeps tile-12 MFMA inputs finite/deterministic)
  if (tid < 256) {
    int row = 200 + (tid >> 5), s = tid & 31;
    int swz = (s & 24) | ((s & 7) ^ (row & 7));
    *(short8*)(smem + P_OFF + row * 512 + swz * 16) = (short8){0, 0, 0, 0, 0, 0, 0, 0};
  }
  __syncthreads();

  // --- register-resident P fragments (B operand): 4 N-tiles x 8 k-steps
  short8 pf[4][8];
#pragma unroll
  for (int nt = 0; nt < 4; ++nt) {
    int prow = (nq * 4 + nt) * 16 + ncol;  // rows 200..207 are zeroed
#pragma unroll
    for (int ks = 0; ks < 8; ++ks) {
      int slot = ks * 4 + kg;
      int swz = (slot & 24) | ((slot & 7) ^ (prow & 7));
      pf[nt][ks] = *(const short8*)(smem + P_OFF + prow * 512 + swz * 16);
    }
  }

  // --- octet gather setup: 8 lanes per pair, slice so = tid&7
  const int so = tid & 7, p0 = tid >> 3;  // p0 in 0..63
  int ip[8], jp[8];
  float s_surr = 0.f, s_sep = 0.f;

#pragma unroll 1
  for (int ct = 0; ct < 8; ++ct) {
    if ((ct & 3) == 0) {  // (re)load this flavor's 8 pairs per thread
      const int* pr = (ct < 4) ? cpairs : xpairs;
#pragma unroll
      for (int k = 0; k < 8; ++k) {
        int2 pp = *(const int2*)(pr + 2 * (p0 + 64 * k));
        ip[k] = pp.x; jp[k] = pp.y;
      }
    }
    // ---- MFMA: T[prow][kcol] = sum_h Dcat[h][ct*64+kcol] * P[prow][h]
    // A = Dcat-col frags (from global, L1/L2-hot), B = P-row frags (regs)
    float4_ acc[4][2];
#pragma unroll
    for (int nt = 0; nt < 4; ++nt)
#pragma unroll
      for (int mt = 0; mt < 2; ++mt) acc[nt][mt] = (float4_){0.f, 0.f, 0.f, 0.f};
#pragma unroll
    for (int ks = 0; ks < 8; ++ks) {
      short8 af[2];
#pragma unroll
      for (int mt = 0; mt < 2; ++mt) {
        int c = ct * 64 + mg * 32 + mt * 16 + ncol;
        af[mt] = *(const short8*)(DcatT + c * HDIM + ks * 32 + kg * 8);
      }
#pragma unroll
      for (int nt = 0; nt < 4; ++nt)
#pragma unroll
        for (int mt = 0; mt < 2; ++mt)
          acc[nt][mt] = __builtin_amdgcn_mfma_f32_16x16x32_bf16(af[mt], pf[nt][ks],
                                                                acc[nt][mt], 0, 0, 0);
    }
    // ---- T writes into buffer ct&1: lane kcol = mg*32+mt*16+kg*4 (+reg)
    unsigned char* Tbuf = smem + T_OFF + (ct & 1) * TBYTES;
#pragma unroll
    for (int nt = 0; nt < 4; ++nt) {
      int prow = (nq * 4 + nt) * 16 + ncol;
#pragma unroll
      for (int mt = 0; mt < 2; ++mt) {
        uint2_ pk;
        pk[0] = (unsigned int)f2b(acc[nt][mt][0]) | ((unsigned int)f2b(acc[nt][mt][1]) << 16);
        pk[1] = (unsigned int)f2b(acc[nt][mt][2]) | ((unsigned int)f2b(acc[nt][mt][3]) << 16);
        int slot = (mg * 32 + mt * 16 + kg * 4) >> 3;  // 16B slot 0..7
        int off8 = (kg & 1) * 8;
        *(uint2_*)(Tbuf + prow * TSTRIDE + ((slot ^ (prow & 7)) << 4) + off8) = pk;
      }
    }
    __syncthreads();  // T[ct&1] visible (prev buffer's gather finished pre-write)

    // ---- octet gather: thread covers slice so of 8 pairs
    float g = 0.f;
#pragma unroll
    for (int k = 0; k < 8; ++k) {
      const int i = ip[k], j = jp[k];
      uint4_ tv = *(const uint4_*)(Tbuf + i * TSTRIDE + ((so ^ (i & 7)) << 4));
      int q = ((ct & 3) * 8) | (so ^ (j & 7));
      uint4_ pv = *(const uint4_*)(smem + P_OFF + j * 512 + (q << 4));
      g = dot8acc(tv, pv, g);
    }
    if (ct < 4) s_surr += g; else s_sep += g;
  }

  // ---- block reduction + atomics
#pragma unroll
  for (int off = 32; off > 0; off >>= 1) {
    s_surr += __shfl_down(s_surr, off);
    s_sep  += __shfl_down(s_sep, off);
    lnode  += __shfl_down(lnode, off);
  }
  float* red = (float*)(smem + RED_OFF);
  if (lane == 0) { red[wave] = s_surr; red[8 + wave] = s_sep; }
  __syncthreads();
  if (lane == 0 && wave == 0) {
    // stash lnode partials via second pass through red[] is avoided: reduce
    // lnode with one more LDS slot set
  }
  __syncthreads();
  if (lane == 0) ((float*)(smem + RED_OFF))[0] = red[0];  // no-op keep layout
  // (lnode handled below with its own slots)
  if (lane == 0) red[8 + 8 + wave] = lnode;  // hmm-free: slots 16..23 exist? RED 64B=16 floats
  __syncthreads();
  if (tid == 0) {
    float a = 0.f, c = 0.f;
    for (int w = 0; w < 8; ++w) { a += red[w]; c += red[8 + w]; }
    atomicAdd(&ws[0], a);
    atomicAdd(&ws[1], c);
  }
  // lnode: slots 16..23 are beyond the 64B scratch; reduce via shfl across
  // waves using atomics directly (8 atomics/block, negligible)
  if (lane == 0) atomicAdd(&ws[2], lnode);
}

// ------------------------------ final combine -------------------------------
__global__ void s2l_final(const float* __restrict__ ws, float* __restrict__ out) {
  if (threadIdx.x == 0) {
    const float inv_be = 1.f / (512.f * 512.f);
    float l_surr = ws[0] * inv_be;
    float l_sep = -ws[1] * inv_be;
    float l_node = -ws[2] / 512.f;
    out[0] = l_surr + 0.3f * l_node + 0.1f * l_sep;
    out[1] = l_surr;
    out[2] = l_node;
    out[3] = l_sep;
  }
}

extern "C" void kernel_launch(void* const* d_in, const int* in_sizes, int n_in,
                              void* d_out, int out_size, void* d_ws, size_t ws_size,
                              hipStream_t stream) {
  (void)in_sizes; (void)n_in; (void)out_size; (void)ws_size;
  const float* P     = (const float*)d_in[0];
  const float* d_err = (const float*)d_in[1];
  const float* d_hw  = (const float*)d_in[2];
  const float* feat  = (const float*)d_in[3];
  const float* qi    = (const float*)d_in[4];
  const float* W1    = (const float*)d_in[5];
  const float* bias1 = (const float*)d_in[6];
  const float* W2    = (const float*)d_in[7];
  const float* bias2 = (const float*)d_in[8];
  const int* cpairs  = (const int*)d_in[9];
  const int* xpairs  = (const int*)d_in[10];
  float* ws = (float*)d_ws;
  unsigned short* DcatT = (unsigned short*)((char*)d_ws + WS_DCAT_BYTE_OFF);
  float* out = (float*)d_out;

  hipMemsetAsync(d_ws, 0, 64, stream);  // accumulators + dmax slot (poison-safe)
  s2l_prep<<<dim3(65), dim3(256), 0, stream>>>(feat, W1, bias1, W2, bias2, qi, d_hw, ws);
  s2l_dcat<<<dim3(8, 4), dim3(256), 0, stream>>>(d_err, d_hw, ws, DcatT);
  s2l_main<<<dim3(512), dim3(512), 0, stream>>>(P, cpairs, xpairs, qi, ws, DcatT);
  s2l_final<<<dim3(1), dim3(64), 0, stream>>>(ws, out);
}

// Round 4
// 275.543 us; speedup vs baseline: 1.4496x; 1.2311x over previous
//
#include <hip/hip_runtime.h>

// ---------------------------------------------------------------------------
// Stage2Loss v4:
//   - 256 blocks x 1024 threads (16 waves/CU, one grid round); each block
//     does batches b and b+256 sequentially. LDS: P bf16 swizzled + T dbuf.
//   - D operand pre-permuted into MFMA-fragment order in global (Dfrag):
//     every af load is a fully-coalesced 1KB dwordx4, L2-hot chip-wide.
//   - raw d_hw in the GEMM (normalization deferred to the final scalar) ->
//     pre-kernel has no internal dependency; 3 graph nodes total.
//   - final combine folded into s2l_main via atomic block counter.
// ---------------------------------------------------------------------------

typedef __attribute__((ext_vector_type(8))) short short8;
typedef __attribute__((ext_vector_type(4))) float float4_;
typedef __attribute__((ext_vector_type(2))) unsigned int uint2_;
typedef __attribute__((ext_vector_type(4))) unsigned int uint4_;

#define HDIM 256
#define LDIM 200

// ws float-index layout:
//  [0] S_surr [1] S_sep [2] S_node [3] inv_qi_sum [5] dhw_max(uint) [6] counter
//  [16..271] q[256]
//  byte 2048: Dfrag bf16, 256 chunks x 64 lanes x 8 halves (256 KB)
//    chunk = ((c64*2+mg)*2+mt)*8+ks ; lane = kg*16+ncol ; halves e=0..7
//    value = Dcat[h=ks*32+kg*8+e][c=c64*64+mg*32+mt*16+ncol]
//    (Dcat = [d_error | d_hw_RAW], 256 x 512)
#define WS_DFRAG_BYTE_OFF 2048

__device__ __forceinline__ unsigned short f2b(float f) {  // RNE f32->bf16
  unsigned int u = __float_as_uint(f);
  return (unsigned short)((u + 0x7FFFu + ((u >> 16) & 1u)) >> 16);
}

#if defined(__has_builtin)
#if __has_builtin(__builtin_amdgcn_fdot2_f32_bf16)
#define HAVE_FDOT2 1
#endif
#endif
#ifdef HAVE_FDOT2
typedef __attribute__((ext_vector_type(2))) __bf16 bf16x2;
#endif

__device__ __forceinline__ float dot8acc(uint4_ a, uint4_ b, float acc) {
#ifdef HAVE_FDOT2
#pragma unroll
  for (int d = 0; d < 4; ++d) {
    union { unsigned int u; bf16x2 v; } ua, ub;
    ua.u = a[d]; ub.u = b[d];
    acc = __builtin_amdgcn_fdot2_f32_bf16(ua.v, ub.v, acc, false);
  }
#else
#pragma unroll
  for (int d = 0; d < 4; ++d) {
    float alo = __uint_as_float(a[d] << 16);
    float ahi = __uint_as_float(a[d] & 0xffff0000u);
    float blo = __uint_as_float(b[d] << 16);
    float bhi = __uint_as_float(b[d] & 0xffff0000u);
    acc = fmaf(alo, blo, acc);
    acc = fmaf(ahi, bhi, acc);
  }
#endif
  return acc;
}

// ---------------- pre: block0 = MLP + qi-sum; blocks 1..32 = Dfrag ----------
__global__ void s2l_pre(const float* __restrict__ feat, const float* __restrict__ W1,
                        const float* __restrict__ bias1, const float* __restrict__ W2,
                        const float* __restrict__ bias2, const float* __restrict__ qi,
                        const float* __restrict__ derr, const float* __restrict__ dhw,
                        float* __restrict__ ws, unsigned short* __restrict__ Dfrag) {
  const int tid = threadIdx.x;  // 256
  if (blockIdx.x == 0) {
    __shared__ float red[4];
    float f0 = feat[tid * 5 + 0], f1 = feat[tid * 5 + 1], f2 = feat[tid * 5 + 2];
    float f3 = feat[tid * 5 + 3], f4 = feat[tid * 5 + 4];
    float s = bias2[0];
#pragma unroll
    for (int j = 0; j < 32; ++j) {
      float hd = bias1[j] + f0 * W1[j] + f1 * W1[32 + j] + f2 * W1[64 + j] +
                 f3 * W1[96 + j] + f4 * W1[128 + j];
      s += fmaxf(hd, 0.f) * W2[j];
    }
    ws[16 + tid] = 1.f / (1.f + expf(-s));
    float v = (tid < LDIM) ? qi[tid] : 0.f;
#pragma unroll
    for (int off = 32; off > 0; off >>= 1) v += __shfl_down(v, off);
    if ((tid & 63) == 0) red[tid >> 6] = v;
    __syncthreads();
    if (tid == 0) ws[3] = 1.f / fmaxf(red[0] + red[1] + red[2] + red[3], 1e-8f);
    return;
  }
  // ---- Dfrag builder: tile (c64, ht) = 64 Dcat-cols x 64 h-rows ----
  __shared__ float tile[64][65];
  const int bid = blockIdx.x - 1;      // 0..31
  const int c64 = bid >> 2;            // 0..7 (0..3 err, 4..7 hw raw)
  const int ht = bid & 3;              // 0..3 (h-row group)
  const float* src = (c64 < 4) ? derr : dhw;
  const int c0 = (c64 & 3) * 64;
  float m = 0.f;
#pragma unroll
  for (int k = 0; k < 16; ++k) {
    int idx = k * 256 + tid;
    int lh = idx >> 6, lc = idx & 63;
    float v = src[(ht * 64 + lh) * 256 + c0 + lc];
    tile[lh][lc] = v;
    m = fmaxf(m, v);
  }
  if (c64 >= 4) {  // contribute to global d_hw max
#pragma unroll
    for (int off = 32; off > 0; off >>= 1) m = fmaxf(m, __shfl_down(m, off));
    if ((tid & 63) == 0) atomicMax(((unsigned int*)ws) + 5, __float_as_uint(m));
  }
  __syncthreads();
  // write fragment-order chunks: thread -> (g-group of 8 h, one col)
  const int lc = tid & 63;                   // col within tile
  const int mg = lc >> 5, mt = (lc >> 4) & 1, ncol = lc & 15;
#pragma unroll
  for (int it = 0; it < 2; ++it) {
    const int g = it * 4 + (tid >> 6);       // 0..7 : 8-h group
    const int h0 = g * 8;                    // within-tile h base
    const int ks = ht * 2 + (g >> 2);        // global k-step
    const int kg = g & 3;
    const int lane = kg * 16 + ncol;
    short8 v;
#pragma unroll
    for (int e = 0; e < 8; ++e) v[e] = (short)f2b(tile[h0 + e][lc]);
    const int chunk = ((c64 * 2 + mg) * 2 + mt) * 8 + ks;
    *(short8*)(Dfrag + (size_t)chunk * 512 + lane * 8) = v;
  }
}

// ------------------------------- main kernel --------------------------------
// LDS: P 200x256 bf16 swizzled (100KB) | T dbuf 2 x 208x64 bf16 | reduce
#define P_OFF 0
#define T_OFF 102400
#define TSTRIDE 128
#define TBYTES (208 * TSTRIDE)                    // 26624
#define RED_OFF (T_OFF + 2 * TBYTES)              // 155648
#define LDS_BYTES (RED_OFF + 192)

__global__ __launch_bounds__(1024) void s2l_main(
    const float* __restrict__ P, const int* __restrict__ cpairs,
    const int* __restrict__ xpairs, const float* __restrict__ qi,
    float* __restrict__ ws, const unsigned short* __restrict__ Dfrag,
    float* __restrict__ out) {
  __shared__ __attribute__((aligned(16))) unsigned char smem[LDS_BYTES];
  const int tid = threadIdx.x;
  const int wave = tid >> 6, lane = tid & 63;
  const int ncol = lane & 15, kg = lane >> 4;
  const int rt0 = wave >> 1;            // 0..7   (row-tile, N side)
  const int mg = wave & 1;              // 0..1   (32-col half, M side)
  const bool v1 = (rt0 + 8 < 13);       // second row-tile valid (rt0<5)
  const int prow0 = rt0 * 16 + ncol;
  const int prow1 = (rt0 + 8) * 16 + ncol;  // may touch rows>=200: garbage OK,
                                            // flows only to T rows >=200 (never gathered)
  const int so = tid & 7, oct = tid >> 3;   // octet gather: 128 octets
  const float inv_qs = ws[3];

  float s_surr = 0.f, s_sep = 0.f, lnode = 0.f;

#pragma unroll 1
  for (int bb = 0; bb < 2; ++bb) {
    const int b = blockIdx.x + bb * 256;
    const float* Pb = P + (size_t)b * (HDIM * HDIM);

    // ---- q slice (slot s = tid&31, loop-invariant since 1024%32==0) ----
    const int s0q = (tid & 31) * 8;
    float qreg[8];
#pragma unroll
    for (int e = 0; e < 8; ++e) qreg[e] = ws[16 + s0q + e];

    // ---- stage P_log[b] -> bf16 LDS (swizzled) + fused l_node ----
    for (int sg = tid; sg < LDIM * 32; sg += 1024) {  // 6400 16B-slots
      int row = sg >> 5, s = sg & 31;
      float4_ a0 = *(const float4_*)(Pb + row * HDIM + s * 8);
      float4_ a1 = *(const float4_*)(Pb + row * HDIM + s * 8 + 4);
      short8 v;
      v[0] = (short)f2b(a0[0]); v[1] = (short)f2b(a0[1]);
      v[2] = (short)f2b(a0[2]); v[3] = (short)f2b(a0[3]);
      v[4] = (short)f2b(a1[0]); v[5] = (short)f2b(a1[1]);
      v[6] = (short)f2b(a1[2]); v[7] = (short)f2b(a1[3]);
      int swz = (s & 24) | ((s & 7) ^ (row & 7));
      *(short8*)(smem + P_OFF + row * 512 + swz * 16) = v;
      float vq = a0[0] * qreg[0] + a0[1] * qreg[1] + a0[2] * qreg[2] + a0[3] * qreg[3] +
                 a1[0] * qreg[4] + a1[1] * qreg[5] + a1[2] * qreg[6] + a1[3] * qreg[7];
      lnode += vq * (qi[row] * inv_qs);
    }
    __syncthreads();

    // ---- register-resident P fragments (B operand): 2 row-tiles x 8 ks ----
    short8 pf[2][8];
#pragma unroll
    for (int ks = 0; ks < 8; ++ks) {
      {
        int slot = ks * 4 + kg;
        int swz = (slot & 24) | ((slot & 7) ^ (prow0 & 7));
        pf[0][ks] = *(const short8*)(smem + P_OFF + prow0 * 512 + swz * 16);
      }
      {
        int slot = ks * 4 + kg;
        int swz = (slot & 24) | ((slot & 7) ^ (prow1 & 7));
        pf[1][ks] = *(const short8*)(smem + P_OFF + prow1 * 512 + swz * 16);
      }
    }

    int ip[4], jp[4];
#pragma unroll 1
    for (int ct = 0; ct < 8; ++ct) {
      if ((ct & 3) == 0) {  // load this flavor's 4 pairs per thread
        const int* pr = (ct < 4) ? cpairs : xpairs;
#pragma unroll
        for (int k = 0; k < 4; ++k) {
          int2 pp = *(const int2*)(pr + 2 * (oct + 128 * k));
          ip[k] = pp.x; jp[k] = pp.y;
        }
      }
      // ---- MFMA: T[prow][kcol] = sum_h Dcat[h][ct*64+kcol] * P[prow][h]
      // A = Dfrag chunks (coalesced 1KB loads, L2-hot), B = pf (registers)
      float4_ acc[2][2];
#pragma unroll
      for (int nt = 0; nt < 2; ++nt)
#pragma unroll
        for (int mt = 0; mt < 2; ++mt) acc[nt][mt] = (float4_){0.f, 0.f, 0.f, 0.f};
#pragma unroll
      for (int ks = 0; ks < 8; ++ks) {
        short8 af[2];
#pragma unroll
        for (int mt = 0; mt < 2; ++mt) {
          const int chunk = ((ct * 2 + mg) * 2 + mt) * 8 + ks;
          af[mt] = *(const short8*)(Dfrag + (size_t)chunk * 512 + lane * 8);
        }
#pragma unroll
        for (int mt = 0; mt < 2; ++mt)
          acc[0][mt] = __builtin_amdgcn_mfma_f32_16x16x32_bf16(af[mt], pf[0][ks],
                                                               acc[0][mt], 0, 0, 0);
        if (v1) {
#pragma unroll
          for (int mt = 0; mt < 2; ++mt)
            acc[1][mt] = __builtin_amdgcn_mfma_f32_16x16x32_bf16(af[mt], pf[1][ks],
                                                                 acc[1][mt], 0, 0, 0);
        }
      }
      // ---- T writes: lane kcol = mg*32+mt*16+kg*4 (+reg), row = prow ----
      unsigned char* Tbuf = smem + T_OFF + (ct & 1) * TBYTES;
#pragma unroll
      for (int nt = 0; nt < 2; ++nt) {
        if (nt == 1 && !v1) break;  // wave-uniform
        const int prow = nt ? prow1 : prow0;
#pragma unroll
        for (int mt = 0; mt < 2; ++mt) {
          uint2_ pk;
          pk[0] = (unsigned int)f2b(acc[nt][mt][0]) | ((unsigned int)f2b(acc[nt][mt][1]) << 16);
          pk[1] = (unsigned int)f2b(acc[nt][mt][2]) | ((unsigned int)f2b(acc[nt][mt][3]) << 16);
          const int slot = (mg * 32 + mt * 16 + kg * 4) >> 3;
          const int off8 = (kg & 1) * 8;
          *(uint2_*)(Tbuf + prow * TSTRIDE + ((slot ^ (prow & 7)) << 4) + off8) = pk;
        }
      }
      __syncthreads();  // T[ct&1] visible; other buffer's gather already done

      // ---- octet gather: slice so of 4 pairs; T (LDS) . P-slice (LDS) ----
      float g = 0.f;
#pragma unroll
      for (int k = 0; k < 4; ++k) {
        const int i = ip[k], j = jp[k];
        uint4_ tv = *(const uint4_*)(Tbuf + i * TSTRIDE + ((so ^ (i & 7)) << 4));
        const int q = ((ct & 3) * 8) | (so ^ (j & 7));
        uint4_ pv = *(const uint4_*)(smem + P_OFF + j * 512 + (q << 4));
        g = dot8acc(tv, pv, g);
      }
      if (ct < 4) s_surr += g; else s_sep += g;
    }
    __syncthreads();  // all P/T reads done before next batch restages
  }

  // ---- block reduction ----
#pragma unroll
  for (int off = 32; off > 0; off >>= 1) {
    s_surr += __shfl_down(s_surr, off);
    s_sep  += __shfl_down(s_sep, off);
    lnode  += __shfl_down(lnode, off);
  }
  float* red = (float*)(smem + RED_OFF);
  if (lane == 0) { red[wave] = s_surr; red[16 + wave] = s_sep; red[32 + wave] = lnode; }
  __syncthreads();
  if (tid == 0) {
    float a = 0.f, c = 0.f, l = 0.f;
    for (int w = 0; w < 16; ++w) { a += red[w]; c += red[16 + w]; l += red[32 + w]; }
    atomicAdd(&ws[0], a);
    atomicAdd(&ws[1], c);
    atomicAdd(&ws[2], l);
    __threadfence();
    unsigned int done = atomicAdd(((unsigned int*)ws) + 6, 1u);
    if (done == 255u) {  // last block: fold in the final combine
      float S_surr = atomicAdd(&ws[0], 0.f);
      float S_sep  = atomicAdd(&ws[1], 0.f);
      float S_node = atomicAdd(&ws[2], 0.f);
      float mx = __uint_as_float(((unsigned int*)ws)[5]);
      const float inv_be = 1.f / (512.f * 512.f);
      float l_surr = S_surr * inv_be;
      float l_sep = -(S_sep * inv_be) / fmaxf(mx, 1e-8f);
      float l_node = -S_node / 512.f;
      out[0] = l_surr + 0.3f * l_node + 0.1f * l_sep;
      out[1] = l_surr;
      out[2] = l_node;
      out[3] = l_sep;
    }
  }
}

extern "C" void kernel_launch(void* const* d_in, const int* in_sizes, int n_in,
                              void* d_out, int out_size, void* d_ws, size_t ws_size,
                              hipStream_t stream) {
  (void)in_sizes; (void)n_in; (void)out_size; (void)ws_size;
  const float* P     = (const float*)d_in[0];
  const float* d_err = (const float*)d_in[1];
  const float* d_hw  = (const float*)d_in[2];
  const float* feat  = (const float*)d_in[3];
  const float* qi    = (const float*)d_in[4];
  const float* W1    = (const float*)d_in[5];
  const float* bias1 = (const float*)d_in[6];
  const float* W2    = (const float*)d_in[7];
  const float* bias2 = (const float*)d_in[8];
  const int* cpairs  = (const int*)d_in[9];
  const int* xpairs  = (const int*)d_in[10];
  float* ws = (float*)d_ws;
  unsigned short* Dfrag = (unsigned short*)((char*)d_ws + WS_DFRAG_BYTE_OFF);
  float* out = (float*)d_out;

  hipMemsetAsync(d_ws, 0, 64, stream);  // accums + dmax + counter (poison-safe)
  s2l_pre<<<dim3(33), dim3(256), 0, stream>>>(feat, W1, bias1, W2, bias2, qi,
                                              d_err, d_hw, ws, Dfrag);
  s2l_main<<<dim3(256), dim3(1024), 0, stream>>>(P, cpairs, xpairs, qi, ws, Dfrag, out);
}